// Round 2
// baseline (519.960 us; speedup 1.0000x reference)
//
#include <hip/hip_runtime.h>
#include <hip/hip_bf16.h>

constexpr int kB = 16, kN = 512, kD = 256, kH = 8, kE = 16, kDH = 32;

typedef float f4 __attribute__((ext_vector_type(4)));
typedef __bf16 bf8 __attribute__((ext_vector_type(8)));

// ---------------- P1: cast h (fp32) -> bf16 ----------------
__global__ __launch_bounds__(256) void cast_h_kernel(const float* __restrict__ h,
                                                     __bf16* __restrict__ hb) {
  const int idx = (blockIdx.x * 256 + threadIdx.x) * 8;
  f4 a = *(const f4*)(h + idx);
  f4 b = *(const f4*)(h + idx + 4);
  bf8 o;
  o[0] = (__bf16)a[0]; o[1] = (__bf16)a[1]; o[2] = (__bf16)a[2]; o[3] = (__bf16)a[3];
  o[4] = (__bf16)b[0]; o[5] = (__bf16)b[1]; o[6] = (__bf16)b[2]; o[7] = (__bf16)b[3];
  *(bf8*)(hb + idx) = o;
}

// ---------------- P2: weights -> bf16, transposed [n][k] ----------------
// Wt rows 0..255 = Wq cols, 256..511 = Wk cols, 512..767 = Wv cols; Wot = Wo^T.
__global__ __launch_bounds__(256) void prep_w_kernel(
    const float* __restrict__ Wq, const float* __restrict__ Wk,
    const float* __restrict__ Wv, const float* __restrict__ Wo,
    __bf16* __restrict__ Wt, __bf16* __restrict__ Wot) {
  const int r = blockIdx.x;
  const int t = threadIdx.x;
  if (r < 768) {
    const float* src = (r < 256) ? Wq : (r < 512) ? Wk : Wv;
    const int c = r & 255;
    Wt[(size_t)r * 256 + t] = (__bf16)src[(size_t)t * 256 + c];
  } else {
    const int rr = r - 768;
    Wot[(size_t)rr * 256 + t] = (__bf16)Wo[(size_t)t * 256 + rr];
  }
}

// ---------------- K1: QKV projection GEMM (M=8192, N=768, K=256) ----------------
// 128x64 tile, 4 waves (2x2), direct-global bf16 fragments, no LDS.
// Epilogue: +bias; q scaled by 1/sqrt(32); v stored TRANSPOSED [b][h][d][n].
__global__ __launch_bounds__(256, 4) void qkv_gemm_kernel(
    const __bf16* __restrict__ hb, const __bf16* __restrict__ Wt,
    const float* __restrict__ bq, const float* __restrict__ bk,
    const float* __restrict__ bv,
    __bf16* __restrict__ qw, __bf16* __restrict__ kw, __bf16* __restrict__ vtw) {
  const int M0 = blockIdx.x * 128;
  const int N0 = blockIdx.y * 64;
  const int tid = threadIdx.x;
  const int wave = tid >> 6, lane = tid & 63;
  const int l15 = lane & 15, lq = lane >> 4;
  const int wm = wave & 1, wn = wave >> 1;
  const f4 fzero = {0.f, 0.f, 0.f, 0.f};

  f4 acc[4][2];
#pragma unroll
  for (int tm = 0; tm < 4; ++tm)
#pragma unroll
    for (int tn = 0; tn < 2; ++tn) acc[tm][tn] = fzero;

#pragma unroll
  for (int kk = 0; kk < 256; kk += 32) {
    bf8 af[4], bfr[2];
#pragma unroll
    for (int tm = 0; tm < 4; ++tm)
      af[tm] = *(const bf8*)(hb + (size_t)(M0 + wm * 64 + tm * 16 + l15) * 256 + kk + lq * 8);
#pragma unroll
    for (int tn = 0; tn < 2; ++tn)
      bfr[tn] = *(const bf8*)(Wt + (size_t)(N0 + wn * 32 + tn * 16 + l15) * 256 + kk + lq * 8);
#pragma unroll
    for (int tm = 0; tm < 4; ++tm)
#pragma unroll
      for (int tn = 0; tn < 2; ++tn)
        acc[tm][tn] = __builtin_amdgcn_mfma_f32_16x16x32_bf16(af[tm], bfr[tn], acc[tm][tn], 0, 0, 0);
  }

  const float QS = 0.17677669529663687f;  // 1/sqrt(DH)
  const int wsel = N0 >> 8;               // 0:q 1:k 2:v (uniform per block)
#pragma unroll
  for (int tn = 0; tn < 2; ++tn) {
    const int n = N0 + wn * 32 + tn * 16 + l15;
    const int c = n & 255;
    const float bias = (wsel == 0) ? bq[c] : (wsel == 1) ? bk[c] : bv[c];
#pragma unroll
    for (int tm = 0; tm < 4; ++tm) {
#pragma unroll
      for (int r = 0; r < 4; ++r) {
        const int m = M0 + wm * 64 + tm * 16 + lq * 4 + r;
        const float v = acc[tm][tn][r] + bias;
        if (wsel == 0) {
          qw[(size_t)m * 256 + c] = (__bf16)(v * QS);
        } else if (wsel == 1) {
          kw[(size_t)m * 256 + c] = (__bf16)v;
        } else {
          const int b_ = m >> 9, nn_ = m & 511, hh = c >> 5, dd = c & 31;
          vtw[(((size_t)b_ * kH + hh) * kDH + dd) * kN + nn_] = (__bf16)v;
        }
      }
    }
  }
}

// ---------------- K2: fused pos + QK^T + softmax + attn-write + P@V ----------------
// Grid: 512 blocks (b, 16-query tile). 8 waves = 8 heads. Scores in 128 VGPR/lane.
// NOTE: masks arrive as int32 (harness materializes bool as int).
__global__ __launch_bounds__(512, 2) void attn_fused_kernel(
    const __bf16* __restrict__ qw, const __bf16* __restrict__ kw,
    const __bf16* __restrict__ vtw, const float* __restrict__ edges,
    const int* __restrict__ dmask, const int* __restrict__ kmask,
    const float* __restrict__ Wp, const float* __restrict__ bp,
    float* __restrict__ attn_out, __bf16* __restrict__ ow) {
  const int blk = blockIdx.x;
  const int b = blk >> 5;
  const int n0 = (blk & 31) * 16;
  const int tid = threadIdx.x;
  const int wave = tid >> 6, lane = tid & 63;
  const int l15 = lane & 15, lq = lane >> 4;

  // pos chunk buffer unioned with P (bf16) buffer; disjoint lifetimes.
  __shared__ union {
    float pos[8][16][132];   // [h][q][m_local], m padded 128->132 (bank spread)
    __bf16 p[8][16][136];    // [h][q][m_local], m padded 128->136 (16B-aligned rows)
  } su;

  f4 sc[32];  // scores: sc[kt][r] = S[q = lq*4+r][key = kt*16+l15]
  const float RS8 = 0.35355339059327373f;  // 1/sqrt(H)
  float bph[8];
#pragma unroll
  for (int hh = 0; hh < 8; ++hh) bph[hh] = bp[hh] * RS8;

  // ---- phase 1: pos = (edges*RS8)@Wp + bp*RS8, mask folded in as -1e9; init sc ----
  const int mq = tid >> 7;   // 0..3  (query group)
  const int mm = tid & 127;  // key within chunk
#pragma unroll
  for (int cc = 0; cc < 4; ++cc) {
    const int m0 = cc * 128;
    const int km = kmask[b * kN + m0 + mm];
    float accp[4][8];
#pragma unroll
    for (int qq = 0; qq < 4; ++qq)
#pragma unroll
      for (int hh = 0; hh < 8; ++hh) accp[qq][hh] = bph[hh];

#pragma unroll
    for (int e4 = 0; e4 < 4; ++e4) {
      f4 ed[4];
#pragma unroll
      for (int qq = 0; qq < 4; ++qq) {
        const int q = mq * 4 + qq;
        ed[qq] = *(const f4*)(edges + ((size_t)(b * kN + n0 + q) * kN + m0 + mm) * kE + e4 * 4);
        ed[qq] *= RS8;
      }
#pragma unroll
      for (int i = 0; i < 4; ++i) {
#pragma unroll
        for (int hh = 0; hh < 8; ++hh) {
          const float w = Wp[(e4 * 4 + i) * kH + hh];  // uniform -> s_load path
#pragma unroll
          for (int qq = 0; qq < 4; ++qq) accp[qq][hh] = fmaf(ed[qq][i], w, accp[qq][hh]);
        }
      }
    }
#pragma unroll
    for (int qq = 0; qq < 4; ++qq) {
      const int q = mq * 4 + qq;
      const bool valid = (dmask[(size_t)(b * kN + n0 + q) * kN + m0 + mm] != 0) && (km != 0);
#pragma unroll
      for (int hh = 0; hh < 8; ++hh)
        su.pos[hh][q][mm] = valid ? accp[qq][hh] : -1e9f;
    }
    __syncthreads();
#pragma unroll
    for (int kl = 0; kl < 8; ++kl)
#pragma unroll
      for (int r = 0; r < 4; ++r)
        sc[cc * 8 + kl][r] = su.pos[wave][lq * 4 + r][kl * 16 + l15];
    __syncthreads();
  }

  // ---- phase 2: scores += q . k^T (MFMA accumulates onto pos init) ----
  bf8 qa = *(const bf8*)(qw + ((size_t)(b * kN + n0 + l15) * kH + wave) * kDH + lq * 8);
#pragma unroll
  for (int kt = 0; kt < 32; ++kt) {
    bf8 kb = *(const bf8*)(kw + ((size_t)(b * kN + kt * 16 + l15) * kH + wave) * kDH + lq * 8);
    sc[kt] = __builtin_amdgcn_mfma_f32_16x16x32_bf16(qa, kb, sc[kt], 0, 0, 0);
  }

  // ---- phase 3: row softmax (cross-lane over 16 lanes sharing a row) ----
  float inv[4];
#pragma unroll
  for (int r = 0; r < 4; ++r) {
    float m_ = sc[0][r];
#pragma unroll
    for (int kt = 1; kt < 32; ++kt) m_ = fmaxf(m_, sc[kt][r]);
#pragma unroll
    for (int s = 1; s < 16; s <<= 1) m_ = fmaxf(m_, __shfl_xor(m_, s, 16));
    float s_ = 0.f;
#pragma unroll
    for (int kt = 0; kt < 32; ++kt) {
      const float e_ = __expf(sc[kt][r] - m_);
      sc[kt][r] = e_;
      s_ += e_;
    }
#pragma unroll
    for (int s = 1; s < 16; s <<= 1) s_ += __shfl_xor(s_, s, 16);
    inv[r] = 1.0f / s_;
  }

  // ---- phase 4: write attn (fp32), P->LDS (bf16, wave-private), P@V MFMA ----
  const f4 fzero = {0.f, 0.f, 0.f, 0.f};
  f4 oacc[2];
  oacc[0] = fzero; oacc[1] = fzero;
  float* attn_base = attn_out + ((size_t)(b * kH + wave) * kN + n0) * kN;
#pragma unroll
  for (int cc = 0; cc < 4; ++cc) {
#pragma unroll
    for (int kl = 0; kl < 8; ++kl) {
      const int kt = cc * 8 + kl;
#pragma unroll
      for (int r = 0; r < 4; ++r) {
        const float p = sc[kt][r] * inv[r];
        attn_base[(size_t)(lq * 4 + r) * kN + kt * 16 + l15] = p;
        su.p[wave][lq * 4 + r][kl * 16 + l15] = (__bf16)p;
      }
    }
    // Same-wave cross-lane LDS RAW: force write completion and forbid the
    // compiler from hoisting the ds_reads above the ds_writes.
    __asm__ __volatile__("s_waitcnt lgkmcnt(0)" ::: "memory");
#pragma unroll
    for (int mc = 0; mc < 4; ++mc) {
      bf8 pa = *(const bf8*)(&su.p[wave][l15][mc * 32 + lq * 8]);
#pragma unroll
      for (int dd = 0; dd < 2; ++dd) {
        bf8 vb = *(const bf8*)(vtw + (((size_t)(b * kH + wave) * kDH) + dd * 16 + l15) * kN +
                               cc * 128 + mc * 32 + lq * 8);
        oacc[dd] = __builtin_amdgcn_mfma_f32_16x16x32_bf16(pa, vb, oacc[dd], 0, 0, 0);
      }
    }
  }

  // ---- phase 5: store O (bf16) for the output projection ----
#pragma unroll
  for (int dd = 0; dd < 2; ++dd)
#pragma unroll
    for (int r = 0; r < 4; ++r)
      ow[(size_t)(b * kN + n0 + lq * 4 + r) * kD + wave * kDH + dd * 16 + l15] = (__bf16)oacc[dd][r];
}

// ---------------- K3: out = O @ Wo + bo (M=8192, N=256, K=256) ----------------
__global__ __launch_bounds__(256, 4) void out_gemm_kernel(
    const __bf16* __restrict__ ob, const __bf16* __restrict__ Wot,
    const float* __restrict__ bo, float* __restrict__ out) {
  const int M0 = blockIdx.x * 128;
  const int N0 = blockIdx.y * 64;
  const int tid = threadIdx.x;
  const int wave = tid >> 6, lane = tid & 63;
  const int l15 = lane & 15, lq = lane >> 4;
  const int wm = wave & 1, wn = wave >> 1;
  const f4 fzero = {0.f, 0.f, 0.f, 0.f};

  f4 acc[4][2];
#pragma unroll
  for (int tm = 0; tm < 4; ++tm)
#pragma unroll
    for (int tn = 0; tn < 2; ++tn) acc[tm][tn] = fzero;

#pragma unroll
  for (int kk = 0; kk < 256; kk += 32) {
    bf8 af[4], bfr[2];
#pragma unroll
    for (int tm = 0; tm < 4; ++tm)
      af[tm] = *(const bf8*)(ob + (size_t)(M0 + wm * 64 + tm * 16 + l15) * 256 + kk + lq * 8);
#pragma unroll
    for (int tn = 0; tn < 2; ++tn)
      bfr[tn] = *(const bf8*)(Wot + (size_t)(N0 + wn * 32 + tn * 16 + l15) * 256 + kk + lq * 8);
#pragma unroll
    for (int tm = 0; tm < 4; ++tm)
#pragma unroll
      for (int tn = 0; tn < 2; ++tn)
        acc[tm][tn] = __builtin_amdgcn_mfma_f32_16x16x32_bf16(af[tm], bfr[tn], acc[tm][tn], 0, 0, 0);
  }

#pragma unroll
  for (int tn = 0; tn < 2; ++tn) {
    const int n = N0 + wn * 32 + tn * 16 + l15;
    const float bias = bo[n];
#pragma unroll
    for (int tm = 0; tm < 4; ++tm)
#pragma unroll
      for (int r = 0; r < 4; ++r) {
        const int m = M0 + wm * 64 + tm * 16 + lq * 4 + r;
        out[(size_t)m * 256 + n] = acc[tm][tn][r] + bias;
      }
  }
}

extern "C" void kernel_launch(void* const* d_in, const int* in_sizes, int n_in,
                              void* d_out, int out_size, void* d_ws, size_t ws_size,
                              hipStream_t stream) {
  const float* h = (const float*)d_in[0];
  const float* edges = (const float*)d_in[1];
  const int* dmask = (const int*)d_in[2];
  const int* kmask = (const int*)d_in[3];
  const float* Wq = (const float*)d_in[4];
  const float* bq = (const float*)d_in[5];
  const float* Wk = (const float*)d_in[6];
  const float* bk = (const float*)d_in[7];
  const float* Wv = (const float*)d_in[8];
  const float* bv = (const float*)d_in[9];
  const float* Wo = (const float*)d_in[10];
  const float* bo = (const float*)d_in[11];
  const float* Wp = (const float*)d_in[12];
  const float* bp = (const float*)d_in[13];

  char* ws = (char*)d_ws;
  __bf16* hb = (__bf16*)(ws);                                // 4 MB (reused as ow)
  __bf16* Wt = (__bf16*)(ws + ((size_t)4 << 20));            // 384 KB
  __bf16* Wot = (__bf16*)(ws + ((size_t)4 << 20) + 768 * 256 * 2);  // 128 KB
  __bf16* qw = (__bf16*)(ws + ((size_t)5 << 20));            // 4 MB
  __bf16* kw = (__bf16*)(ws + ((size_t)9 << 20));            // 4 MB
  __bf16* vtw = (__bf16*)(ws + ((size_t)13 << 20));          // 4 MB
  __bf16* ow = hb;  // h cast is consumed by qkv_gemm before attn writes O

  float* out = (float*)d_out;
  float* attn = out + (size_t)kB * kN * kD;

  cast_h_kernel<<<1024, 256, 0, stream>>>(h, hb);
  prep_w_kernel<<<1024, 256, 0, stream>>>(Wq, Wk, Wv, Wo, Wt, Wot);
  qkv_gemm_kernel<<<dim3(64, 12), 256, 0, stream>>>(hb, Wt, bq, bk, bv, qw, kw, vtw);
  attn_fused_kernel<<<512, 512, 0, stream>>>(qw, kw, vtw, edges, dmask, kmask, Wp, bp, attn, ow);
  out_gemm_kernel<<<dim3(64, 4), 256, 0, stream>>>(ow, Wot, bo, out);
}